// Round 1
// baseline (881.691 us; speedup 1.0000x reference)
//
#include <hip/hip_runtime.h>

#define B_      8
#define N_      1024
#define DIN_    64
#define H_      128
#define MSG2    128
#define L_      5
#define TGT_    12
#define NLAYERS_ 3
#define CAT_    640          // L_ * MSG2
#define NODES   (B_ * N_)    // 8192

__device__ __forceinline__ float sigmoidf_(float x) { return 1.f / (1.f + __expf(-x)); }

// ---------------- init: pad h_in -> h0/h, compute masks ----------------
__global__ __launch_bounds__(256) void k_init(const float* __restrict__ h_in,
                                              float* __restrict__ h,
                                              float* __restrict__ h0,
                                              float* __restrict__ maskA,
                                              float* __restrict__ maskR) {
  int node = blockIdx.x * 4 + (threadIdx.x >> 6);
  int lane = threadIdx.x & 63;
  float v = h_in[(size_t)node * DIN_ + lane];
  size_t base = (size_t)node * H_;
  h[base + lane] = v;   h[base + 64 + lane] = 0.f;
  h0[base + lane] = v;  h0[base + 64 + lane] = 0.f;
  float sa = fabsf(v), ss = v;
  for (int off = 32; off > 0; off >>= 1) {
    sa += __shfl_down(sa, off);
    ss += __shfl_down(ss, off);
  }
  if (lane == 0) {
    maskA[node] = (sa > 0.f) ? 1.f : 0.f;
    maskR[node] = (ss > 0.f) ? 1.f : 0.f;
  }
}

// ---------------- Acat[d][l*128+o] = A[l][d][o] ----------------
__global__ __launch_bounds__(256) void k_acat(const float* __restrict__ A,
                                              float* __restrict__ Acat) {
  int idx = blockIdx.x * 256 + threadIdx.x;
  if (idx >= 128 * CAT_) return;
  int d = idx / CAT_;
  int c = idx - d * CAT_;
  int l = c >> 7, o = c & 127;
  Acat[idx] = A[((size_t)l * 128 + d) * 128 + o];
}

// ---------------- Mcat[8192][640] = h[8192][128] @ Acat[128][640] ----------------
__global__ __launch_bounds__(256) void k_gemm(const float* __restrict__ X,
                                              const float* __restrict__ W,
                                              float* __restrict__ C) {
  __shared__ float At[32][64];   // [k][row]
  __shared__ float Bt[32][64];   // [k][col]
  const int tx = threadIdx.x & 15;
  const int ty = threadIdx.x >> 4;
  const int r0 = blockIdx.y * 64;
  const int c0 = blockIdx.x * 64;
  float acc[4][4] = {};
  const int q    = threadIdx.x * 8;
  const int srow = q >> 5;          // 0..63
  const int sk0  = q & 31;          // 0,8,16,24
  const int bk   = threadIdx.x >> 3;        // 0..31
  const int bc   = (threadIdx.x & 7) * 8;   // 0..56
  for (int kc = 0; kc < 128; kc += 32) {
    const float* xs = X + (size_t)(r0 + srow) * 128 + kc + sk0;
    float4 a0 = *(const float4*)xs;
    float4 a1 = *(const float4*)(xs + 4);
    At[sk0+0][srow] = a0.x; At[sk0+1][srow] = a0.y;
    At[sk0+2][srow] = a0.z; At[sk0+3][srow] = a0.w;
    At[sk0+4][srow] = a1.x; At[sk0+5][srow] = a1.y;
    At[sk0+6][srow] = a1.z; At[sk0+7][srow] = a1.w;
    const float* wsrc = W + (size_t)(kc + bk) * CAT_ + c0 + bc;
    *(float4*)&Bt[bk][bc]     = *(const float4*)wsrc;
    *(float4*)&Bt[bk][bc + 4] = *(const float4*)(wsrc + 4);
    __syncthreads();
    #pragma unroll
    for (int k = 0; k < 32; ++k) {
      float4 av = *(const float4*)&At[k][ty * 4];
      float4 bv = *(const float4*)&Bt[k][tx * 4];
      acc[0][0] += av.x*bv.x; acc[0][1] += av.x*bv.y; acc[0][2] += av.x*bv.z; acc[0][3] += av.x*bv.w;
      acc[1][0] += av.y*bv.x; acc[1][1] += av.y*bv.y; acc[1][2] += av.y*bv.z; acc[1][3] += av.y*bv.w;
      acc[2][0] += av.z*bv.x; acc[2][1] += av.z*bv.y; acc[2][2] += av.z*bv.z; acc[2][3] += av.z*bv.w;
      acc[3][0] += av.w*bv.x; acc[3][1] += av.w*bv.y; acc[3][2] += av.w*bv.z; acc[3][3] += av.w*bv.w;
    }
    __syncthreads();
  }
  #pragma unroll
  for (int i = 0; i < 4; ++i) {
    float4 v = make_float4(acc[i][0], acc[i][1], acc[i][2], acc[i][3]);
    *(float4*)&C[(size_t)(r0 + ty*4 + i) * CAT_ + c0 + tx*4] = v;
  }
}

// ---------------- agg[b,v,o] = sum_w g[b,v,w] * Mcat[b,w,e*128+o] ----------------
#define TW_ 64
__global__ __launch_bounds__(512) void k_agg(const float* __restrict__ g,
                                             const int* __restrict__ e,
                                             const float* __restrict__ Mcat,
                                             float* __restrict__ agg) {
  __shared__ float Gt[32][TW_];
  __shared__ int   Et[32][TW_];
  const int b  = blockIdx.y;
  const int v0 = blockIdx.x * 32;
  const int t  = threadIdx.x;
  const int ol = t & 31;       // o-lane: o = 4*ol..4*ol+3
  const int vg = t >> 5;       // 0..15
  float4 acc0 = {0.f,0.f,0.f,0.f};
  float4 acc1 = {0.f,0.f,0.f,0.f};
  const int svi = t >> 4;            // 0..31
  const int swc = (t & 15) * 4;      // 0..60
  const float* grow = g + ((size_t)b * N_ + v0 + svi) * N_;
  const int*   erow = e + ((size_t)b * N_ + v0 + svi) * N_;
  for (int w0 = 0; w0 < N_; w0 += TW_) {
    *(float4*)&Gt[svi][swc] = *(const float4*)(grow + w0 + swc);
    *(int4*)&Et[svi][swc]   = *(const int4*)(erow + w0 + swc);
    __syncthreads();
    for (int w = 0; w < TW_; ++w) {
      const float* mrow = Mcat + ((size_t)b * N_ + w0 + w) * CAT_;
      {
        float gw = Gt[vg][w]; int lw = Et[vg][w];
        float4 m = *(const float4*)(mrow + lw * MSG2 + ol * 4);
        acc0.x += gw*m.x; acc0.y += gw*m.y; acc0.z += gw*m.z; acc0.w += gw*m.w;
      }
      {
        float gw = Gt[vg + 16][w]; int lw = Et[vg + 16][w];
        float4 m = *(const float4*)(mrow + lw * MSG2 + ol * 4);
        acc1.x += gw*m.x; acc1.y += gw*m.y; acc1.z += gw*m.z; acc1.w += gw*m.w;
      }
    }
    __syncthreads();
  }
  ((float4*)(agg + ((size_t)b * N_ + v0 + vg) * MSG2))[ol] = acc0;
  ((float4*)(agg + ((size_t)b * N_ + v0 + vg + 16) * MSG2))[ol] = acc1;
}

// ---------------- fused GRU: h = GRU(agg, h) * mask ----------------
__global__ __launch_bounds__(128) void k_gru(const float* __restrict__ agg,
                                             const float* __restrict__ hbuf,
                                             const float* __restrict__ Wi,
                                             const float* __restrict__ Wh,
                                             const float* __restrict__ bi,
                                             const float* __restrict__ bh,
                                             const float* __restrict__ maskA,
                                             float* __restrict__ hout) {
  __shared__ float smT[128 * 20];   // [d][n], pitch 20 (float4-aligned, conflict-reduced)
  __shared__ float shT[128 * 20];
  const int j  = threadIdx.x;       // channel 0..127
  const int n0 = blockIdx.x * 16;
  #pragma unroll
  for (int n = 0; n < 16; ++n) {
    smT[j * 20 + n] = agg[((size_t)n0 + n) * 128 + j];
    shT[j * 20 + n] = hbuf[((size_t)n0 + n) * 128 + j];
  }
  __syncthreads();
  float ir[16], iz[16], inn[16], hr[16], hz[16], hn[16];
  const float bir = bi[j], biz = bi[128 + j], bin = bi[256 + j];
  const float bhr = bh[j], bhz = bh[128 + j], bhn = bh[256 + j];
  #pragma unroll
  for (int n = 0; n < 16; ++n) {
    ir[n] = bir; iz[n] = biz; inn[n] = bin;
    hr[n] = bhr; hz[n] = bhz; hn[n]  = bhn;
  }
  for (int d = 0; d < 128; ++d) {
    const float* wi = Wi + d * 384;
    const float* wh = Wh + d * 384;
    float wir = wi[j], wiz = wi[128 + j], win = wi[256 + j];
    float whr = wh[j], whz = wh[128 + j], whn = wh[256 + j];
    #pragma unroll
    for (int qq = 0; qq < 4; ++qq) {
      float4 mv = *(const float4*)&smT[d * 20 + qq * 4];
      float4 hv = *(const float4*)&shT[d * 20 + qq * 4];
      ir[qq*4+0] += mv.x*wir; iz[qq*4+0] += mv.x*wiz; inn[qq*4+0] += mv.x*win;
      hr[qq*4+0] += hv.x*whr; hz[qq*4+0] += hv.x*whz; hn[qq*4+0]  += hv.x*whn;
      ir[qq*4+1] += mv.y*wir; iz[qq*4+1] += mv.y*wiz; inn[qq*4+1] += mv.y*win;
      hr[qq*4+1] += hv.y*whr; hz[qq*4+1] += hv.y*whz; hn[qq*4+1]  += hv.y*whn;
      ir[qq*4+2] += mv.z*wir; iz[qq*4+2] += mv.z*wiz; inn[qq*4+2] += mv.z*win;
      hr[qq*4+2] += hv.z*whr; hz[qq*4+2] += hv.z*whz; hn[qq*4+2]  += hv.z*whn;
      ir[qq*4+3] += mv.w*wir; iz[qq*4+3] += mv.w*wiz; inn[qq*4+3] += mv.w*win;
      hr[qq*4+3] += hv.w*whr; hz[qq*4+3] += hv.w*whz; hn[qq*4+3]  += hv.w*whn;
    }
  }
  #pragma unroll
  for (int n = 0; n < 16; ++n) {
    float r  = sigmoidf_(ir[n] + hr[n]);
    float z  = sigmoidf_(iz[n] + hz[n]);
    float nn = tanhf(inn[n] + r * hn[n]);
    float hv = shT[j * 20 + n];
    float m  = maskA[n0 + n];
    hout[((size_t)n0 + n) * 128 + j] = ((1.f - z) * nn + z * hv) * m;
  }
}

// ---------------- readout ----------------
__global__ __launch_bounds__(256) void k_read(const float* __restrict__ h,
                                              const float* __restrict__ h0,
                                              const float* __restrict__ maskR,
                                              const float* __restrict__ Wg,
                                              const float* __restrict__ bg,
                                              const float* __restrict__ Wo,
                                              const float* __restrict__ bo,
                                              float* __restrict__ out) {
  __shared__ float sacc[TGT_];
  if (threadIdx.x < TGT_) sacc[threadIdx.x] = 0.f;
  __syncthreads();
  int node = blockIdx.x * 4 + (threadIdx.x >> 6);
  int lane = threadIdx.x & 63;
  int b = node >> 10;
  size_t base = (size_t)node * H_;
  float x0 = h[base + lane],  x1 = h[base + 64 + lane];
  float x2 = h0[base + lane], x3 = h0[base + 64 + lane];
  float rm = maskR[node];
  for (int t = 0; t < TGT_; ++t) {
    float p1 = x0 * Wg[lane * TGT_ + t] + x1 * Wg[(lane + 64) * TGT_ + t]
             + x2 * Wg[(128 + lane) * TGT_ + t] + x3 * Wg[(192 + lane) * TGT_ + t];
    float p2 = x0 * Wo[lane * TGT_ + t] + x1 * Wo[(lane + 64) * TGT_ + t];
    for (int off = 32; off > 0; off >>= 1) {
      p1 += __shfl_xor(p1, off);
      p2 += __shfl_xor(p2, off);
    }
    if (lane == 0) {
      float val = sigmoidf_(p1 + bg[t]) * (p2 + bo[t]) * rm;
      atomicAdd(&sacc[t], val);
    }
  }
  __syncthreads();
  if (threadIdx.x < TGT_) atomicAdd(&out[b * TGT_ + threadIdx.x], sacc[threadIdx.x]);
}

extern "C" void kernel_launch(void* const* d_in, const int* in_sizes, int n_in,
                              void* d_out, int out_size, void* d_ws, size_t ws_size,
                              hipStream_t stream) {
  (void)in_sizes; (void)n_in; (void)out_size; (void)ws_size;
  const float* g    = (const float*)d_in[0];
  const float* h_in = (const float*)d_in[1];
  const int*   e    = (const int*)d_in[2];
  const float* A    = (const float*)d_in[3];
  const float* Wi   = (const float*)d_in[4];
  const float* Wh   = (const float*)d_in[5];
  const float* bi   = (const float*)d_in[6];
  const float* bh   = (const float*)d_in[7];
  const float* Wg   = (const float*)d_in[8];
  const float* bg   = (const float*)d_in[9];
  const float* Wo   = (const float*)d_in[10];
  const float* bo   = (const float*)d_in[11];
  float* out = (float*)d_out;
  float* ws  = (float*)d_ws;

  float* h     = ws;
  float* h0    = h + (size_t)NODES * H_;
  float* maskA = h0 + (size_t)NODES * H_;
  float* maskR = maskA + NODES;
  float* Acat  = maskR + NODES;
  float* agg   = Acat + 128 * CAT_;
  float* Mcat  = agg + (size_t)NODES * MSG2;

  k_init<<<NODES / 4, 256, 0, stream>>>(h_in, h, h0, maskA, maskR);
  k_acat<<<(128 * CAT_ + 255) / 256, 256, 0, stream>>>(A, Acat);
  for (int layer = 0; layer < NLAYERS_; ++layer) {
    k_gemm<<<dim3(CAT_ / 64, NODES / 64), 256, 0, stream>>>(h, Acat, Mcat);
    k_agg<<<dim3(N_ / 32, B_), 512, 0, stream>>>(g, e, Mcat, agg);
    k_gru<<<NODES / 16, 128, 0, stream>>>(agg, h, Wi, Wh, bi, bh, maskA, h);
  }
  hipMemsetAsync(d_out, 0, (size_t)B_ * TGT_ * sizeof(float), stream);
  k_read<<<NODES / 4, 256, 0, stream>>>(h, h0, maskR, Wg, bg, Wo, bo, out);
}

// Round 2
// 416.991 us; speedup vs baseline: 2.1144x; 2.1144x over previous
//
#include <hip/hip_runtime.h>

#define B_      8
#define N_      1024
#define DIN_    64
#define H_      128
#define MSG2    128
#define L_      5
#define TGT_    12
#define NLAYERS_ 3
#define CAT_    640          // L_ * MSG2
#define NODES   (B_ * N_)    // 8192

typedef __attribute__((ext_vector_type(8))) short s16x8;
typedef __attribute__((ext_vector_type(4))) float f32x4;

__device__ __forceinline__ float sigmoidf_(float x) { return 1.f / (1.f + __expf(-x)); }

__device__ __forceinline__ unsigned short f2bf(float x) {
  unsigned int u = __float_as_uint(x);
  u += 0x7FFFu + ((u >> 16) & 1u);      // round-to-nearest-even
  return (unsigned short)(u >> 16);
}

// ---------------- init: pad h_in -> h0/h, compute masks ----------------
__global__ __launch_bounds__(256) void k_init(const float* __restrict__ h_in,
                                              float* __restrict__ h,
                                              float* __restrict__ h0,
                                              float* __restrict__ maskA,
                                              float* __restrict__ maskR) {
  int node = blockIdx.x * 4 + (threadIdx.x >> 6);
  int lane = threadIdx.x & 63;
  float v = h_in[(size_t)node * DIN_ + lane];
  size_t base = (size_t)node * H_;
  h[base + lane] = v;   h[base + 64 + lane] = 0.f;
  h0[base + lane] = v;  h0[base + 64 + lane] = 0.f;
  float sa = fabsf(v), ss = v;
  for (int off = 32; off > 0; off >>= 1) {
    sa += __shfl_down(sa, off);
    ss += __shfl_down(ss, off);
  }
  if (lane == 0) {
    maskA[node] = (sa > 0.f) ? 1.f : 0.f;
    maskR[node] = (ss > 0.f) ? 1.f : 0.f;
  }
}

// ---------------- Acat[d][l*128+o] = A[l][d][o] ----------------
__global__ __launch_bounds__(256) void k_acat(const float* __restrict__ A,
                                              float* __restrict__ Acat) {
  int idx = blockIdx.x * 256 + threadIdx.x;
  if (idx >= 128 * CAT_) return;
  int d = idx / CAT_;
  int c = idx - d * CAT_;
  int l = c >> 7, o = c & 127;
  Acat[idx] = A[((size_t)l * 128 + d) * 128 + o];
}

// ---------------- McatT[b][l][o][w] = bf16( sum_d h[b,w,d] * Acat[d][l*128+o] ) ----------------
__global__ __launch_bounds__(256) void k_gemmT(const float* __restrict__ h,
                                               const float* __restrict__ Acat,
                                               unsigned short* __restrict__ McatT) {
  __shared__ float At[32 * 64];       // [k][c]
  __shared__ float Ht[32 * 68];       // [k][n], pad 4
  const int tid = threadIdx.x;
  const int c0 = blockIdx.x * 64;
  const int n0 = blockIdx.y * 64;
  const int b  = n0 >> 10;
  const int w0 = n0 & 1023;
  const int tx = tid & 15, ty = tid >> 4;
  const int ar = tid >> 3;            // 0..31 (k)
  const int ac = (tid & 7) * 8;       // c chunk
  const int hr = tid >> 2;            // 0..63 (n)
  const int hq = (tid & 3) * 8;       // k chunk
  float acc[4][4] = {};
  for (int kb = 0; kb < 128; kb += 32) {
    const float* as = Acat + (size_t)(kb + ar) * CAT_ + c0 + ac;
    *(float4*)&At[ar * 64 + ac]     = *(const float4*)as;
    *(float4*)&At[ar * 64 + ac + 4] = *(const float4*)(as + 4);
    const float* hs = h + (size_t)(n0 + hr) * H_ + kb + hq;
    float4 h0v = *(const float4*)hs;
    float4 h1v = *(const float4*)(hs + 4);
    Ht[(hq + 0) * 68 + hr] = h0v.x; Ht[(hq + 1) * 68 + hr] = h0v.y;
    Ht[(hq + 2) * 68 + hr] = h0v.z; Ht[(hq + 3) * 68 + hr] = h0v.w;
    Ht[(hq + 4) * 68 + hr] = h1v.x; Ht[(hq + 5) * 68 + hr] = h1v.y;
    Ht[(hq + 6) * 68 + hr] = h1v.z; Ht[(hq + 7) * 68 + hr] = h1v.w;
    __syncthreads();
    #pragma unroll
    for (int k = 0; k < 32; ++k) {
      float4 av = *(const float4*)&At[k * 64 + ty * 4];
      float4 bv = *(const float4*)&Ht[k * 68 + tx * 4];
      acc[0][0] += av.x*bv.x; acc[0][1] += av.x*bv.y; acc[0][2] += av.x*bv.z; acc[0][3] += av.x*bv.w;
      acc[1][0] += av.y*bv.x; acc[1][1] += av.y*bv.y; acc[1][2] += av.y*bv.z; acc[1][3] += av.y*bv.w;
      acc[2][0] += av.z*bv.x; acc[2][1] += av.z*bv.y; acc[2][2] += av.z*bv.z; acc[2][3] += av.z*bv.w;
      acc[3][0] += av.w*bv.x; acc[3][1] += av.w*bv.y; acc[3][2] += av.w*bv.z; acc[3][3] += av.w*bv.w;
    }
    __syncthreads();
  }
  #pragma unroll
  for (int i = 0; i < 4; ++i) {
    int c = c0 + ty * 4 + i;
    int l = c >> 7, o = c & 127;
    ushort4 v;
    v.x = f2bf(acc[i][0]); v.y = f2bf(acc[i][1]);
    v.z = f2bf(acc[i][2]); v.w = f2bf(acc[i][3]);
    *(ushort4*)&McatT[(((size_t)b * L_ + l) * MSG2 + o) * N_ + w0 + tx * 4] = v;
  }
}

// ---------------- agg via 5 masked bf16 MFMA GEMMs ----------------
// aggP[ks][b,v,o] = sum_{w in ks-half} sum_l (e==l ? g : 0)[v,w] * McatT[b][l][o][w]
__global__ __launch_bounds__(256) void k_agg_mfma(const float* __restrict__ g,
                                                  const int* __restrict__ e,
                                                  const unsigned short* __restrict__ McatT,
                                                  float* __restrict__ aggP) {
  __shared__ __align__(16) unsigned short Gt[64 * 40];   // bf16 g-tile, pitch 40
  __shared__ __align__(16) unsigned char  Et[64 * 40];   // labels u8, pitch 40
  __shared__ __align__(16) unsigned short Bl[L_][128 * 40];
  const int tid  = threadIdx.x;
  const int v0   = blockIdx.x * 64;
  const int ks   = blockIdx.y;         // K split 0..1
  const int b    = blockIdx.z;
  const int wid  = tid >> 6, lane = tid & 63;
  const int wr   = wid >> 1, wc = wid & 1;   // wave tile: 32 rows x 64 cols
  const int lr   = lane & 15, lg = lane >> 4;

  f32x4 acc[2][4];
  #pragma unroll
  for (int m = 0; m < 2; ++m)
    #pragma unroll
    for (int n = 0; n < 4; ++n) acc[m][n] = {0.f, 0.f, 0.f, 0.f};

  const int ar = tid >> 2;            // 0..63 (A-stage row)
  const int aq = (tid & 3) * 8;       // k-chunk of 8
  const int br = tid >> 1;            // 0..127 (B-stage row)
  const int bq = (tid & 1) * 16;      // k-chunk of 16
  const size_t grow = ((size_t)b * N_ + v0 + ar) * N_;

  for (int kk = 0; kk < 16; ++kk) {
    const int kbase = ks * 512 + kk * 32;
    // ---- stage A: g (bf16) + e (u8) ----
    {
      const float* gp = g + grow + kbase + aq;
      const int*   ep = e + grow + kbase + aq;
      float4 g0 = *(const float4*)gp, g1 = *(const float4*)(gp + 4);
      int4   e0 = *(const int4*)ep,  e1 = *(const int4*)(ep + 4);
      s16x8 gv;
      gv[0] = (short)f2bf(g0.x); gv[1] = (short)f2bf(g0.y);
      gv[2] = (short)f2bf(g0.z); gv[3] = (short)f2bf(g0.w);
      gv[4] = (short)f2bf(g1.x); gv[5] = (short)f2bf(g1.y);
      gv[6] = (short)f2bf(g1.z); gv[7] = (short)f2bf(g1.w);
      *(s16x8*)&Gt[ar * 40 + aq] = gv;
      unsigned int ew0 = (unsigned)(e0.x & 0xFF) | ((unsigned)(e0.y & 0xFF) << 8) |
                         ((unsigned)(e0.z & 0xFF) << 16) | ((unsigned)(e0.w & 0xFF) << 24);
      unsigned int ew1 = (unsigned)(e1.x & 0xFF) | ((unsigned)(e1.y & 0xFF) << 8) |
                         ((unsigned)(e1.z & 0xFF) << 16) | ((unsigned)(e1.w & 0xFF) << 24);
      uint2 ewv; ewv.x = ew0; ewv.y = ew1;
      *(uint2*)&Et[ar * 40 + aq] = ewv;
    }
    // ---- stage B: 5 label slices of McatT ----
    #pragma unroll
    for (int l = 0; l < L_; ++l) {
      const unsigned short* mp = McatT + (((size_t)b * L_ + l) * MSG2 + br) * N_ + kbase + bq;
      uint4 b0v = *(const uint4*)mp;
      uint4 b1v = *(const uint4*)(mp + 8);
      *(uint4*)&Bl[l][br * 40 + bq]     = b0v;
      *(uint4*)&Bl[l][br * 40 + bq + 8] = b1v;
    }
    __syncthreads();
    // ---- fragments + masked MFMA ----
    s16x8 gt[2]; uint2 et[2];
    #pragma unroll
    for (int m = 0; m < 2; ++m) {
      int row = wr * 32 + m * 16 + lr;
      gt[m] = *(const s16x8*)&Gt[row * 40 + lg * 8];
      et[m] = *(const uint2*)&Et[row * 40 + lg * 8];
    }
    #pragma unroll
    for (int l = 0; l < L_; ++l) {
      s16x8 bfr[4];
      #pragma unroll
      for (int n = 0; n < 4; ++n) {
        int orow = wc * 64 + n * 16 + lr;
        bfr[n] = *(const s16x8*)&Bl[l][orow * 40 + lg * 8];
      }
      #pragma unroll
      for (int m = 0; m < 2; ++m) {
        unsigned int w0e = et[m].x, w1e = et[m].y;
        s16x8 af;
        af[0] = (((w0e      ) & 0xFFu) == (unsigned)l) ? gt[m][0] : (short)0;
        af[1] = (((w0e >>  8) & 0xFFu) == (unsigned)l) ? gt[m][1] : (short)0;
        af[2] = (((w0e >> 16) & 0xFFu) == (unsigned)l) ? gt[m][2] : (short)0;
        af[3] = (((w0e >> 24) & 0xFFu) == (unsigned)l) ? gt[m][3] : (short)0;
        af[4] = (((w1e      ) & 0xFFu) == (unsigned)l) ? gt[m][4] : (short)0;
        af[5] = (((w1e >>  8) & 0xFFu) == (unsigned)l) ? gt[m][5] : (short)0;
        af[6] = (((w1e >> 16) & 0xFFu) == (unsigned)l) ? gt[m][6] : (short)0;
        af[7] = (((w1e >> 24) & 0xFFu) == (unsigned)l) ? gt[m][7] : (short)0;
        #pragma unroll
        for (int n = 0; n < 4; ++n)
          acc[m][n] = __builtin_amdgcn_mfma_f32_16x16x32_bf16(af, bfr[n], acc[m][n], 0, 0, 0);
      }
    }
    __syncthreads();
  }
  // ---- epilogue: fp32 partial write (C/D layout: col=lane&15, row=(lane>>4)*4+j) ----
  float* op = aggP + ((size_t)ks * NODES + (size_t)b * N_ + v0) * MSG2;
  #pragma unroll
  for (int m = 0; m < 2; ++m)
    #pragma unroll
    for (int n = 0; n < 4; ++n)
      #pragma unroll
      for (int j = 0; j < 4; ++j) {
        int row = wr * 32 + m * 16 + lg * 4 + j;
        int col = wc * 64 + n * 16 + lr;
        op[(size_t)row * MSG2 + col] = acc[m][n][j];
      }
}

// ---------------- fused GRU: h = GRU(sum of 2 agg slabs, h) * mask ----------------
__global__ __launch_bounds__(128) void k_gru(const float* __restrict__ aggP,
                                             const float* __restrict__ hbuf,
                                             const float* __restrict__ Wi,
                                             const float* __restrict__ Wh,
                                             const float* __restrict__ bi,
                                             const float* __restrict__ bh,
                                             const float* __restrict__ maskA,
                                             float* __restrict__ hout) {
  __shared__ float smT[128 * 20];   // [d][n], pitch 20
  __shared__ float shT[128 * 20];
  const int j  = threadIdx.x;       // channel 0..127
  const int n0 = blockIdx.x * 16;
  const size_t slab = (size_t)NODES * MSG2;
  #pragma unroll
  for (int n = 0; n < 16; ++n) {
    size_t ix = ((size_t)n0 + n) * 128 + j;
    smT[j * 20 + n] = aggP[ix] + aggP[slab + ix];
    shT[j * 20 + n] = hbuf[ix];
  }
  __syncthreads();
  float ir[16], iz[16], inn[16], hr[16], hz[16], hn[16];
  const float bir = bi[j], biz = bi[128 + j], bin = bi[256 + j];
  const float bhr = bh[j], bhz = bh[128 + j], bhn = bh[256 + j];
  #pragma unroll
  for (int n = 0; n < 16; ++n) {
    ir[n] = bir; iz[n] = biz; inn[n] = bin;
    hr[n] = bhr; hz[n] = bhz; hn[n]  = bhn;
  }
  for (int d = 0; d < 128; ++d) {
    const float* wi = Wi + d * 384;
    const float* wh = Wh + d * 384;
    float wir = wi[j], wiz = wi[128 + j], win = wi[256 + j];
    float whr = wh[j], whz = wh[128 + j], whn = wh[256 + j];
    #pragma unroll
    for (int qq = 0; qq < 4; ++qq) {
      float4 mv = *(const float4*)&smT[d * 20 + qq * 4];
      float4 hv = *(const float4*)&shT[d * 20 + qq * 4];
      ir[qq*4+0] += mv.x*wir; iz[qq*4+0] += mv.x*wiz; inn[qq*4+0] += mv.x*win;
      hr[qq*4+0] += hv.x*whr; hz[qq*4+0] += hv.x*whz; hn[qq*4+0]  += hv.x*whn;
      ir[qq*4+1] += mv.y*wir; iz[qq*4+1] += mv.y*wiz; inn[qq*4+1] += mv.y*win;
      hr[qq*4+1] += hv.y*whr; hz[qq*4+1] += hv.y*whz; hn[qq*4+1]  += hv.y*whn;
      ir[qq*4+2] += mv.z*wir; iz[qq*4+2] += mv.z*wiz; inn[qq*4+2] += mv.z*win;
      hr[qq*4+2] += hv.z*whr; hz[qq*4+2] += hv.z*whz; hn[qq*4+2]  += hv.z*whn;
      ir[qq*4+3] += mv.w*wir; iz[qq*4+3] += mv.w*wiz; inn[qq*4+3] += mv.w*win;
      hr[qq*4+3] += hv.w*whr; hz[qq*4+3] += hv.w*whz; hn[qq*4+3]  += hv.w*whn;
    }
  }
  #pragma unroll
  for (int n = 0; n < 16; ++n) {
    float r  = sigmoidf_(ir[n] + hr[n]);
    float z  = sigmoidf_(iz[n] + hz[n]);
    float nn = tanhf(inn[n] + r * hn[n]);
    float hv = shT[j * 20 + n];
    float m  = maskA[n0 + n];
    hout[((size_t)n0 + n) * 128 + j] = ((1.f - z) * nn + z * hv) * m;
  }
}

// ---------------- readout ----------------
__global__ __launch_bounds__(256) void k_read(const float* __restrict__ h,
                                              const float* __restrict__ h0,
                                              const float* __restrict__ maskR,
                                              const float* __restrict__ Wg,
                                              const float* __restrict__ bg,
                                              const float* __restrict__ Wo,
                                              const float* __restrict__ bo,
                                              float* __restrict__ out) {
  __shared__ float sacc[TGT_];
  if (threadIdx.x < TGT_) sacc[threadIdx.x] = 0.f;
  __syncthreads();
  int node = blockIdx.x * 4 + (threadIdx.x >> 6);
  int lane = threadIdx.x & 63;
  int b = node >> 10;
  size_t base = (size_t)node * H_;
  float x0 = h[base + lane],  x1 = h[base + 64 + lane];
  float x2 = h0[base + lane], x3 = h0[base + 64 + lane];
  float rm = maskR[node];
  for (int t = 0; t < TGT_; ++t) {
    float p1 = x0 * Wg[lane * TGT_ + t] + x1 * Wg[(lane + 64) * TGT_ + t]
             + x2 * Wg[(128 + lane) * TGT_ + t] + x3 * Wg[(192 + lane) * TGT_ + t];
    float p2 = x0 * Wo[lane * TGT_ + t] + x1 * Wo[(lane + 64) * TGT_ + t];
    for (int off = 32; off > 0; off >>= 1) {
      p1 += __shfl_xor(p1, off);
      p2 += __shfl_xor(p2, off);
    }
    if (lane == 0) {
      float val = sigmoidf_(p1 + bg[t]) * (p2 + bo[t]) * rm;
      atomicAdd(&sacc[t], val);
    }
  }
  __syncthreads();
  if (threadIdx.x < TGT_) atomicAdd(&out[b * TGT_ + threadIdx.x], sacc[threadIdx.x]);
}

extern "C" void kernel_launch(void* const* d_in, const int* in_sizes, int n_in,
                              void* d_out, int out_size, void* d_ws, size_t ws_size,
                              hipStream_t stream) {
  (void)in_sizes; (void)n_in; (void)out_size; (void)ws_size;
  const float* g    = (const float*)d_in[0];
  const float* h_in = (const float*)d_in[1];
  const int*   e    = (const int*)d_in[2];
  const float* A    = (const float*)d_in[3];
  const float* Wi   = (const float*)d_in[4];
  const float* Wh   = (const float*)d_in[5];
  const float* bi   = (const float*)d_in[6];
  const float* bh   = (const float*)d_in[7];
  const float* Wg   = (const float*)d_in[8];
  const float* bg   = (const float*)d_in[9];
  const float* Wo   = (const float*)d_in[10];
  const float* bo   = (const float*)d_in[11];
  float* out = (float*)d_out;
  float* ws  = (float*)d_ws;

  float* h     = ws;                                   // 1,048,576 f
  float* h0    = h + (size_t)NODES * H_;               // 1,048,576 f
  float* maskA = h0 + (size_t)NODES * H_;              // 8192 f
  float* maskR = maskA + NODES;                        // 8192 f
  float* Acat  = maskR + NODES;                        // 81,920 f
  float* aggP  = Acat + 128 * CAT_;                    // 2 * 1,048,576 f
  unsigned short* McatT = (unsigned short*)(aggP + 2 * (size_t)NODES * MSG2); // 5,242,880 us

  k_init<<<NODES / 4, 256, 0, stream>>>(h_in, h, h0, maskA, maskR);
  k_acat<<<(128 * CAT_ + 255) / 256, 256, 0, stream>>>(A, Acat);
  for (int layer = 0; layer < NLAYERS_; ++layer) {
    k_gemmT<<<dim3(CAT_ / 64, NODES / 64), 256, 0, stream>>>(h, Acat, McatT);
    k_agg_mfma<<<dim3(N_ / 64, 2, B_), 256, 0, stream>>>(g, e, McatT, aggP);
    k_gru<<<NODES / 16, 128, 0, stream>>>(aggP, h, Wi, Wh, bi, bh, maskA, h);
  }
  hipMemsetAsync(d_out, 0, (size_t)B_ * TGT_ * sizeof(float), stream);
  k_read<<<NODES / 4, 256, 0, stream>>>(h, h0, maskR, Wg, bg, Wo, bo, out);
}

// Round 5
// 315.817 us; speedup vs baseline: 2.7918x; 1.3204x over previous
//
#include <hip/hip_runtime.h>

#define B_      8
#define N_      1024
#define DIN_    64
#define H_      128
#define MSG2    128
#define L_      5
#define TGT_    12
#define NLAYERS_ 3
#define CAT_    640          // L_ * MSG2
#define NODES   (B_ * N_)    // 8192
#define KSPLIT  4

typedef __attribute__((ext_vector_type(8))) short s16x8;
typedef __attribute__((ext_vector_type(4))) float f32x4;

__device__ __forceinline__ float sigmoidf_(float x) { return 1.f / (1.f + __expf(-x)); }

__device__ __forceinline__ unsigned short f2bf(float x) {
  unsigned int u = __float_as_uint(x);
  u += 0x7FFFu + ((u >> 16) & 1u);      // round-to-nearest-even
  return (unsigned short)(u >> 16);
}

// ---------------- init: pad h_in -> h0/h (fp32), masks ----------------
__global__ __launch_bounds__(256) void k_init(const float* __restrict__ h_in,
                                              float* __restrict__ h,
                                              float* __restrict__ h0,
                                              float* __restrict__ maskA,
                                              float* __restrict__ maskR) {
  int node = blockIdx.x * 4 + (threadIdx.x >> 6);
  int lane = threadIdx.x & 63;
  float v = h_in[(size_t)node * DIN_ + lane];
  size_t base = (size_t)node * H_;
  h[base + lane] = v;   h[base + 64 + lane] = 0.f;
  h0[base + lane] = v;  h0[base + 64 + lane] = 0.f;
  float sa = fabsf(v), ss = v;
  for (int off = 32; off > 0; off >>= 1) {
    sa += __shfl_down(sa, off);
    ss += __shfl_down(ss, off);
  }
  if (lane == 0) {
    maskA[node] = (sa > 0.f) ? 1.f : 0.f;
    maskR[node] = (ss > 0.f) ? 1.f : 0.f;
  }
}

// ---------------- Acat[d][l*128+o] = A[l][d][o]  (fp32) ----------------
__global__ __launch_bounds__(256) void k_acat(const float* __restrict__ A,
                                              float* __restrict__ Acat) {
  int idx = blockIdx.x * 256 + threadIdx.x;
  if (idx >= 128 * CAT_) return;
  int d = idx / CAT_;
  int c = idx - d * CAT_;
  int l = c >> 7, o = c & 127;
  Acat[idx] = A[((size_t)l * 128 + d) * 128 + o];
}

// ---------------- McatT[b][l][o][w] = bf16( sum_d h[b,w,d] * Acat[d][l*128+o] ) ----------------
// fp32 SIMT GEMM (round-2-verified numerics), transposed bf16 output.
__global__ __launch_bounds__(256) void k_gemmT(const float* __restrict__ h,
                                               const float* __restrict__ Acat,
                                               unsigned short* __restrict__ McatT) {
  __shared__ float At[32 * 64];       // [k][c]
  __shared__ float Ht[32 * 68];       // [k][n], pad 4
  const int tid = threadIdx.x;
  const int c0 = blockIdx.x * 64;
  const int n0 = blockIdx.y * 64;
  const int b  = n0 >> 10;
  const int w0 = n0 & 1023;
  const int tx = tid & 15, ty = tid >> 4;
  const int ar = tid >> 3;            // 0..31 (k)
  const int ac = (tid & 7) * 8;       // c chunk
  const int hr = tid >> 2;            // 0..63 (n)
  const int hq = (tid & 3) * 8;       // k chunk
  float acc[4][4] = {};
  for (int kb = 0; kb < 128; kb += 32) {
    const float* as = Acat + (size_t)(kb + ar) * CAT_ + c0 + ac;
    *(float4*)&At[ar * 64 + ac]     = *(const float4*)as;
    *(float4*)&At[ar * 64 + ac + 4] = *(const float4*)(as + 4);
    const float* hs = h + (size_t)(n0 + hr) * H_ + kb + hq;
    float4 h0v = *(const float4*)hs;
    float4 h1v = *(const float4*)(hs + 4);
    Ht[(hq + 0) * 68 + hr] = h0v.x; Ht[(hq + 1) * 68 + hr] = h0v.y;
    Ht[(hq + 2) * 68 + hr] = h0v.z; Ht[(hq + 3) * 68 + hr] = h0v.w;
    Ht[(hq + 4) * 68 + hr] = h1v.x; Ht[(hq + 5) * 68 + hr] = h1v.y;
    Ht[(hq + 6) * 68 + hr] = h1v.z; Ht[(hq + 7) * 68 + hr] = h1v.w;
    __syncthreads();
    #pragma unroll
    for (int k = 0; k < 32; ++k) {
      float4 av = *(const float4*)&At[k * 64 + ty * 4];
      float4 bv = *(const float4*)&Ht[k * 68 + tx * 4];
      acc[0][0] += av.x*bv.x; acc[0][1] += av.x*bv.y; acc[0][2] += av.x*bv.z; acc[0][3] += av.x*bv.w;
      acc[1][0] += av.y*bv.x; acc[1][1] += av.y*bv.y; acc[1][2] += av.y*bv.z; acc[1][3] += av.y*bv.w;
      acc[2][0] += av.z*bv.x; acc[2][1] += av.z*bv.y; acc[2][2] += av.z*bv.z; acc[2][3] += av.z*bv.w;
      acc[3][0] += av.w*bv.x; acc[3][1] += av.w*bv.y; acc[3][2] += av.w*bv.z; acc[3][3] += av.w*bv.w;
    }
    __syncthreads();
  }
  #pragma unroll
  for (int i = 0; i < 4; ++i) {
    int c = c0 + ty * 4 + i;
    int l = c >> 7, o = c & 127;
    ushort4 v;
    v.x = f2bf(acc[i][0]); v.y = f2bf(acc[i][1]);
    v.z = f2bf(acc[i][2]); v.w = f2bf(acc[i][3]);
    *(ushort4*)&McatT[(((size_t)b * L_ + l) * MSG2 + o) * N_ + w0 + tx * 4] = v;
  }
}

// ---------------- agg via 5 masked bf16 MFMA GEMMs, K-split 4 ----------------
__global__ __launch_bounds__(256) void k_agg_mfma(const float* __restrict__ g,
                                                  const int* __restrict__ e,
                                                  const unsigned short* __restrict__ McatT,
                                                  float* __restrict__ aggP) {
  __shared__ __align__(16) unsigned short Gt[64 * 40];
  __shared__ __align__(16) unsigned char  Et[64 * 40];
  __shared__ __align__(16) unsigned short Bl[L_][128 * 40];
  const int tid  = threadIdx.x;
  const int v0   = blockIdx.x * 64;
  const int ks   = blockIdx.y;
  const int b    = blockIdx.z;
  const int wid  = tid >> 6, lane = tid & 63;
  const int wr   = wid >> 1, wc = wid & 1;
  const int lr   = lane & 15, lg = lane >> 4;

  f32x4 acc[2][4];
  #pragma unroll
  for (int m = 0; m < 2; ++m)
    #pragma unroll
    for (int n = 0; n < 4; ++n) acc[m][n] = {0.f, 0.f, 0.f, 0.f};

  const int ar = tid >> 2, aq = (tid & 3) * 8;
  const int br = tid >> 1, bq = (tid & 1) * 16;
  const size_t grow = ((size_t)b * N_ + v0 + ar) * N_;

  for (int kk = 0; kk < 8; ++kk) {
    const int kbase = ks * 256 + kk * 32;
    {
      const float* gp = g + grow + kbase + aq;
      const int*   ep = e + grow + kbase + aq;
      float4 g0 = *(const float4*)gp, g1 = *(const float4*)(gp + 4);
      int4   e0 = *(const int4*)ep,  e1 = *(const int4*)(ep + 4);
      s16x8 gv;
      gv[0] = (short)f2bf(g0.x); gv[1] = (short)f2bf(g0.y);
      gv[2] = (short)f2bf(g0.z); gv[3] = (short)f2bf(g0.w);
      gv[4] = (short)f2bf(g1.x); gv[5] = (short)f2bf(g1.y);
      gv[6] = (short)f2bf(g1.z); gv[7] = (short)f2bf(g1.w);
      *(s16x8*)&Gt[ar * 40 + aq] = gv;
      unsigned int ew0 = (unsigned)(e0.x & 0xFF) | ((unsigned)(e0.y & 0xFF) << 8) |
                         ((unsigned)(e0.z & 0xFF) << 16) | ((unsigned)(e0.w & 0xFF) << 24);
      unsigned int ew1 = (unsigned)(e1.x & 0xFF) | ((unsigned)(e1.y & 0xFF) << 8) |
                         ((unsigned)(e1.z & 0xFF) << 16) | ((unsigned)(e1.w & 0xFF) << 24);
      uint2 ewv; ewv.x = ew0; ewv.y = ew1;
      *(uint2*)&Et[ar * 40 + aq] = ewv;
    }
    #pragma unroll
    for (int l = 0; l < L_; ++l) {
      const unsigned short* mp = McatT + (((size_t)b * L_ + l) * MSG2 + br) * N_ + kbase + bq;
      *(uint4*)&Bl[l][br * 40 + bq]     = *(const uint4*)mp;
      *(uint4*)&Bl[l][br * 40 + bq + 8] = *(const uint4*)(mp + 8);
    }
    __syncthreads();
    s16x8 gt[2]; uint2 et[2];
    #pragma unroll
    for (int m = 0; m < 2; ++m) {
      int row = wr * 32 + m * 16 + lr;
      gt[m] = *(const s16x8*)&Gt[row * 40 + lg * 8];
      et[m] = *(const uint2*)&Et[row * 40 + lg * 8];
    }
    #pragma unroll
    for (int l = 0; l < L_; ++l) {
      s16x8 bfr[4];
      #pragma unroll
      for (int n = 0; n < 4; ++n)
        bfr[n] = *(const s16x8*)&Bl[l][(wc * 64 + n * 16 + lr) * 40 + lg * 8];
      #pragma unroll
      for (int m = 0; m < 2; ++m) {
        unsigned int w0e = et[m].x, w1e = et[m].y;
        s16x8 af;
        af[0] = (((w0e      ) & 0xFFu) == (unsigned)l) ? gt[m][0] : (short)0;
        af[1] = (((w0e >>  8) & 0xFFu) == (unsigned)l) ? gt[m][1] : (short)0;
        af[2] = (((w0e >> 16) & 0xFFu) == (unsigned)l) ? gt[m][2] : (short)0;
        af[3] = (((w0e >> 24) & 0xFFu) == (unsigned)l) ? gt[m][3] : (short)0;
        af[4] = (((w1e      ) & 0xFFu) == (unsigned)l) ? gt[m][4] : (short)0;
        af[5] = (((w1e >>  8) & 0xFFu) == (unsigned)l) ? gt[m][5] : (short)0;
        af[6] = (((w1e >> 16) & 0xFFu) == (unsigned)l) ? gt[m][6] : (short)0;
        af[7] = (((w1e >> 24) & 0xFFu) == (unsigned)l) ? gt[m][7] : (short)0;
        #pragma unroll
        for (int n = 0; n < 4; ++n)
          acc[m][n] = __builtin_amdgcn_mfma_f32_16x16x32_bf16(af, bfr[n], acc[m][n], 0, 0, 0);
      }
    }
    __syncthreads();
  }
  float* op = aggP + ((size_t)ks * NODES + (size_t)b * N_ + v0) * MSG2;
  #pragma unroll
  for (int m = 0; m < 2; ++m)
    #pragma unroll
    for (int n = 0; n < 4; ++n)
      #pragma unroll
      for (int j = 0; j < 4; ++j) {
        int row = wr * 32 + m * 16 + lg * 4 + j;
        int col = wc * 64 + n * 16 + lr;
        op[(size_t)row * MSG2 + col] = acc[m][n][j];
      }
}

// ---------------- xprep: m[node][j] = sum of KSPLIT agg slabs (fp32) ----------------
__global__ __launch_bounds__(256) void k_xprep(const float* __restrict__ aggP,
                                               float* __restrict__ m) {
  const size_t slab = (size_t)NODES * MSG2;
  size_t i4 = ((size_t)blockIdx.x * 256 + threadIdx.x) * 4;
  float4 s0 = *(const float4*)&aggP[i4];
  float4 s1 = *(const float4*)&aggP[slab + i4];
  float4 s2 = *(const float4*)&aggP[2 * slab + i4];
  float4 s3 = *(const float4*)&aggP[3 * slab + i4];
  float4 s;
  s.x = s0.x + s1.x + s2.x + s3.x;
  s.y = s0.y + s1.y + s2.y + s3.y;
  s.z = s0.z + s1.z + s2.z + s3.z;
  s.w = s0.w + s1.w + s2.w + s3.w;
  *(float4*)&m[i4] = s;
}

// ---------------- gates GEMM (fp32 SIMT): gates[row][z*384+c] = X_z @ W_z ----------------
// z=0: X=m, W=Wi (both [.,128]/[128,384]); z=1: X=h, W=Wh.
__global__ __launch_bounds__(256) void k_gates_f32(const float* __restrict__ m,
                                                   const float* __restrict__ h,
                                                   const float* __restrict__ Wi,
                                                   const float* __restrict__ Wh,
                                                   float* __restrict__ gates) {
  __shared__ float At[32][64];   // [k][row]
  __shared__ float Bt[32][64];   // [k][col]
  const int z = blockIdx.z;
  const float* X = z ? h : m;
  const float* W = z ? Wh : Wi;
  const int tx = threadIdx.x & 15;
  const int ty = threadIdx.x >> 4;
  const int r0 = blockIdx.y * 64;
  const int c0 = blockIdx.x * 64;
  float acc[4][4] = {};
  const int q    = threadIdx.x * 8;
  const int srow = q >> 5;          // 0..63
  const int sk0  = q & 31;          // 0,8,16,24
  const int bk   = threadIdx.x >> 3;        // 0..31
  const int bc   = (threadIdx.x & 7) * 8;   // 0..56
  for (int kc = 0; kc < 128; kc += 32) {
    const float* xs = X + (size_t)(r0 + srow) * 128 + kc + sk0;
    float4 a0 = *(const float4*)xs;
    float4 a1 = *(const float4*)(xs + 4);
    At[sk0+0][srow] = a0.x; At[sk0+1][srow] = a0.y;
    At[sk0+2][srow] = a0.z; At[sk0+3][srow] = a0.w;
    At[sk0+4][srow] = a1.x; At[sk0+5][srow] = a1.y;
    At[sk0+6][srow] = a1.z; At[sk0+7][srow] = a1.w;
    const float* wsrc = W + (size_t)(kc + bk) * 384 + c0 + bc;
    *(float4*)&Bt[bk][bc]     = *(const float4*)wsrc;
    *(float4*)&Bt[bk][bc + 4] = *(const float4*)(wsrc + 4);
    __syncthreads();
    #pragma unroll
    for (int k = 0; k < 32; ++k) {
      float4 av = *(const float4*)&At[k][ty * 4];
      float4 bv = *(const float4*)&Bt[k][tx * 4];
      acc[0][0] += av.x*bv.x; acc[0][1] += av.x*bv.y; acc[0][2] += av.x*bv.z; acc[0][3] += av.x*bv.w;
      acc[1][0] += av.y*bv.x; acc[1][1] += av.y*bv.y; acc[1][2] += av.y*bv.z; acc[1][3] += av.y*bv.w;
      acc[2][0] += av.z*bv.x; acc[2][1] += av.z*bv.y; acc[2][2] += av.z*bv.z; acc[2][3] += av.z*bv.w;
      acc[3][0] += av.w*bv.x; acc[3][1] += av.w*bv.y; acc[3][2] += av.w*bv.z; acc[3][3] += av.w*bv.w;
    }
    __syncthreads();
  }
  #pragma unroll
  for (int i = 0; i < 4; ++i) {
    float4 v = make_float4(acc[i][0], acc[i][1], acc[i][2], acc[i][3]);
    *(float4*)&gates[(size_t)(r0 + ty*4 + i) * 768 + z * 384 + c0 + tx*4] = v;
  }
}

// ---------------- GRU elementwise ----------------
__global__ __launch_bounds__(256) void k_gru_elt(const float* __restrict__ gates,
                                                 const float* __restrict__ bi,
                                                 const float* __restrict__ bh,
                                                 const float* __restrict__ maskA,
                                                 float* __restrict__ h) {
  const int t = threadIdx.x;
  const int node = blockIdx.x * 8 + (t >> 5);
  const int j4 = (t & 31) * 4;
  const size_t gb = (size_t)node * 768;
  float4 gir = *(const float4*)&gates[gb + j4];
  float4 giz = *(const float4*)&gates[gb + 128 + j4];
  float4 gin = *(const float4*)&gates[gb + 256 + j4];
  float4 ghr = *(const float4*)&gates[gb + 384 + j4];
  float4 ghz = *(const float4*)&gates[gb + 512 + j4];
  float4 ghn = *(const float4*)&gates[gb + 640 + j4];
  float4 bir = *(const float4*)&bi[j4];
  float4 biz = *(const float4*)&bi[128 + j4];
  float4 bin = *(const float4*)&bi[256 + j4];
  float4 bhr = *(const float4*)&bh[j4];
  float4 bhz = *(const float4*)&bh[128 + j4];
  float4 bhn = *(const float4*)&bh[256 + j4];
  float4 hv = *(const float4*)&h[(size_t)node * 128 + j4];
  float m = maskA[node];
  float4 ho;
  {
    float r = sigmoidf_(gir.x + bir.x + ghr.x + bhr.x);
    float z = sigmoidf_(giz.x + biz.x + ghz.x + bhz.x);
    float nn = tanhf(gin.x + bin.x + r * (ghn.x + bhn.x));
    ho.x = ((1.f - z) * nn + z * hv.x) * m;
  }
  {
    float r = sigmoidf_(gir.y + bir.y + ghr.y + bhr.y);
    float z = sigmoidf_(giz.y + biz.y + ghz.y + bhz.y);
    float nn = tanhf(gin.y + bin.y + r * (ghn.y + bhn.y));
    ho.y = ((1.f - z) * nn + z * hv.y) * m;
  }
  {
    float r = sigmoidf_(gir.z + bir.z + ghr.z + bhr.z);
    float z = sigmoidf_(giz.z + biz.z + ghz.z + bhz.z);
    float nn = tanhf(gin.z + bin.z + r * (ghn.z + bhn.z));
    ho.z = ((1.f - z) * nn + z * hv.z) * m;
  }
  {
    float r = sigmoidf_(gir.w + bir.w + ghr.w + bhr.w);
    float z = sigmoidf_(giz.w + biz.w + ghz.w + bhz.w);
    float nn = tanhf(gin.w + bin.w + r * (ghn.w + bhn.w));
    ho.w = ((1.f - z) * nn + z * hv.w) * m;
  }
  *(float4*)&h[(size_t)node * 128 + j4] = ho;
}

// ---------------- readout ----------------
__global__ __launch_bounds__(256) void k_read(const float* __restrict__ h,
                                              const float* __restrict__ h0,
                                              const float* __restrict__ maskR,
                                              const float* __restrict__ Wg,
                                              const float* __restrict__ bg,
                                              const float* __restrict__ Wo,
                                              const float* __restrict__ bo,
                                              float* __restrict__ out) {
  __shared__ float sacc[TGT_];
  if (threadIdx.x < TGT_) sacc[threadIdx.x] = 0.f;
  __syncthreads();
  int node = blockIdx.x * 4 + (threadIdx.x >> 6);
  int lane = threadIdx.x & 63;
  int b = node >> 10;
  size_t base = (size_t)node * H_;
  float x0 = h[base + lane],  x1 = h[base + 64 + lane];
  float x2 = h0[base + lane], x3 = h0[base + 64 + lane];
  float rm = maskR[node];
  for (int t = 0; t < TGT_; ++t) {
    float p1 = x0 * Wg[lane * TGT_ + t] + x1 * Wg[(lane + 64) * TGT_ + t]
             + x2 * Wg[(128 + lane) * TGT_ + t] + x3 * Wg[(192 + lane) * TGT_ + t];
    float p2 = x0 * Wo[lane * TGT_ + t] + x1 * Wo[(lane + 64) * TGT_ + t];
    for (int off = 32; off > 0; off >>= 1) {
      p1 += __shfl_xor(p1, off);
      p2 += __shfl_xor(p2, off);
    }
    if (lane == 0) {
      float val = sigmoidf_(p1 + bg[t]) * (p2 + bo[t]) * rm;
      atomicAdd(&sacc[t], val);
    }
  }
  __syncthreads();
  if (threadIdx.x < TGT_) atomicAdd(&out[b * TGT_ + threadIdx.x], sacc[threadIdx.x]);
}

extern "C" void kernel_launch(void* const* d_in, const int* in_sizes, int n_in,
                              void* d_out, int out_size, void* d_ws, size_t ws_size,
                              hipStream_t stream) {
  (void)in_sizes; (void)n_in; (void)out_size; (void)ws_size;
  const float* g    = (const float*)d_in[0];
  const float* h_in = (const float*)d_in[1];
  const int*   e    = (const int*)d_in[2];
  const float* A    = (const float*)d_in[3];
  const float* Wi   = (const float*)d_in[4];
  const float* Wh   = (const float*)d_in[5];
  const float* bi   = (const float*)d_in[6];
  const float* bh   = (const float*)d_in[7];
  const float* Wg   = (const float*)d_in[8];
  const float* bg   = (const float*)d_in[9];
  const float* Wo   = (const float*)d_in[10];
  const float* bo   = (const float*)d_in[11];
  float* out = (float*)d_out;
  float* ws  = (float*)d_ws;

  // workspace layout (fp32 elements unless noted):
  float* h     = ws;                                   // 1,048,576
  float* h0    = h + (size_t)NODES * H_;               // 1,048,576
  float* maskA = h0 + (size_t)NODES * H_;              // 8192
  float* maskR = maskA + NODES;                        // 8192
  float* Acat  = maskR + NODES;                        // 81,920
  float* m     = Acat + 128 * CAT_;                    // 1,048,576
  float* aggP  = m + (size_t)NODES * MSG2;             // KSPLIT * 1,048,576 (16.8 MB)
  unsigned short* McatT = (unsigned short*)(aggP + (size_t)KSPLIT * NODES * MSG2); // 5,242,880 us (10.5 MB)
  // gates (8192*768 f = 25.2 MB) overlays aggP+McatT (27.3 MB): aggP dead after
  // k_xprep, McatT dead after k_agg_mfma; next layer's k_gemmT rewrites McatT
  // only after gates is consumed by k_gru_elt.
  float* gates = aggP;

  k_init<<<NODES / 4, 256, 0, stream>>>(h_in, h, h0, maskA, maskR);
  k_acat<<<(128 * CAT_ + 255) / 256, 256, 0, stream>>>(A, Acat);
  for (int layer = 0; layer < NLAYERS_; ++layer) {
    k_gemmT<<<dim3(CAT_ / 64, NODES / 64), 256, 0, stream>>>(h, Acat, McatT);
    k_agg_mfma<<<dim3(N_ / 64, KSPLIT, B_), 256, 0, stream>>>(g, e, McatT, aggP);
    k_xprep<<<(NODES * MSG2 / 4) / 256, 256, 0, stream>>>(aggP, m);
    k_gates_f32<<<dim3(384 / 64, NODES / 64, 2), 256, 0, stream>>>(m, h, Wi, Wh, gates);
    k_gru_elt<<<NODES / 8, 256, 0, stream>>>(gates, bi, bh, maskA, h);
  }
  hipMemsetAsync(d_out, 0, (size_t)B_ * TGT_ * sizeof(float), stream);
  k_read<<<NODES / 4, 256, 0, stream>>>(h, h0, maskR, Wg, bg, Wo, bo, out);
}

// Round 6
// 292.009 us; speedup vs baseline: 3.0194x; 1.0815x over previous
//
#include <hip/hip_runtime.h>

#define B_      8
#define N_      1024
#define DIN_    64
#define H_      128
#define MSG2    128
#define L_      5
#define TGT_    12
#define NLAYERS_ 3
#define CAT_    640          // L_ * MSG2
#define NODES   (B_ * N_)    // 8192
#define KSPLIT  4

typedef __attribute__((ext_vector_type(8))) short s16x8;
typedef __attribute__((ext_vector_type(4))) float f32x4;

__device__ __forceinline__ float sigmoidf_(float x) { return 1.f / (1.f + __expf(-x)); }

__device__ __forceinline__ unsigned short f2bf(float x) {
  unsigned int u = __float_as_uint(x);
  u += 0x7FFFu + ((u >> 16) & 1u);      // round-to-nearest-even
  return (unsigned short)(u >> 16);
}

// ---------------- init: pad h_in -> h0/h (fp32), masks ----------------
__global__ __launch_bounds__(256) void k_init(const float* __restrict__ h_in,
                                              float* __restrict__ h,
                                              float* __restrict__ h0,
                                              float* __restrict__ maskA,
                                              float* __restrict__ maskR) {
  int node = blockIdx.x * 4 + (threadIdx.x >> 6);
  int lane = threadIdx.x & 63;
  float v = h_in[(size_t)node * DIN_ + lane];
  size_t base = (size_t)node * H_;
  h[base + lane] = v;   h[base + 64 + lane] = 0.f;
  h0[base + lane] = v;  h0[base + 64 + lane] = 0.f;
  float sa = fabsf(v), ss = v;
  for (int off = 32; off > 0; off >>= 1) {
    sa += __shfl_down(sa, off);
    ss += __shfl_down(ss, off);
  }
  if (lane == 0) {
    maskA[node] = (sa > 0.f) ? 1.f : 0.f;
    maskR[node] = (ss > 0.f) ? 1.f : 0.f;
  }
}

// ---------------- Acat[d][l*128+o] = A[l][d][o]  (fp32) ----------------
__global__ __launch_bounds__(256) void k_acat(const float* __restrict__ A,
                                              float* __restrict__ Acat) {
  int idx = blockIdx.x * 256 + threadIdx.x;
  if (idx >= 128 * CAT_) return;
  int d = idx / CAT_;
  int c = idx - d * CAT_;
  int l = c >> 7, o = c & 127;
  Acat[idx] = A[((size_t)l * 128 + d) * 128 + o];
}

// ---------------- McatT[b][l][o][w] = bf16( sum_d h[b,w,d] * Acat[d][l*128+o] ) ----------------
__global__ __launch_bounds__(256) void k_gemmT(const float* __restrict__ h,
                                               const float* __restrict__ Acat,
                                               unsigned short* __restrict__ McatT) {
  __shared__ float At[32 * 64];       // [k][c]
  __shared__ float Ht[32 * 68];       // [k][n], pad 4
  const int tid = threadIdx.x;
  const int c0 = blockIdx.x * 64;
  const int n0 = blockIdx.y * 64;
  const int b  = n0 >> 10;
  const int w0 = n0 & 1023;
  const int tx = tid & 15, ty = tid >> 4;
  const int ar = tid >> 3;            // 0..31 (k)
  const int ac = (tid & 7) * 8;       // c chunk
  const int hr = tid >> 2;            // 0..63 (n)
  const int hq = (tid & 3) * 8;       // k chunk
  float acc[4][4] = {};
  for (int kb = 0; kb < 128; kb += 32) {
    const float* as = Acat + (size_t)(kb + ar) * CAT_ + c0 + ac;
    *(float4*)&At[ar * 64 + ac]     = *(const float4*)as;
    *(float4*)&At[ar * 64 + ac + 4] = *(const float4*)(as + 4);
    const float* hs = h + (size_t)(n0 + hr) * H_ + kb + hq;
    float4 h0v = *(const float4*)hs;
    float4 h1v = *(const float4*)(hs + 4);
    Ht[(hq + 0) * 68 + hr] = h0v.x; Ht[(hq + 1) * 68 + hr] = h0v.y;
    Ht[(hq + 2) * 68 + hr] = h0v.z; Ht[(hq + 3) * 68 + hr] = h0v.w;
    Ht[(hq + 4) * 68 + hr] = h1v.x; Ht[(hq + 5) * 68 + hr] = h1v.y;
    Ht[(hq + 6) * 68 + hr] = h1v.z; Ht[(hq + 7) * 68 + hr] = h1v.w;
    __syncthreads();
    #pragma unroll
    for (int k = 0; k < 32; ++k) {
      float4 av = *(const float4*)&At[k * 64 + ty * 4];
      float4 bv = *(const float4*)&Ht[k * 68 + tx * 4];
      acc[0][0] += av.x*bv.x; acc[0][1] += av.x*bv.y; acc[0][2] += av.x*bv.z; acc[0][3] += av.x*bv.w;
      acc[1][0] += av.y*bv.x; acc[1][1] += av.y*bv.y; acc[1][2] += av.y*bv.z; acc[1][3] += av.y*bv.w;
      acc[2][0] += av.z*bv.x; acc[2][1] += av.z*bv.y; acc[2][2] += av.z*bv.z; acc[2][3] += av.z*bv.w;
      acc[3][0] += av.w*bv.x; acc[3][1] += av.w*bv.y; acc[3][2] += av.w*bv.z; acc[3][3] += av.w*bv.w;
    }
    __syncthreads();
  }
  #pragma unroll
  for (int i = 0; i < 4; ++i) {
    int c = c0 + ty * 4 + i;
    int l = c >> 7, o = c & 127;
    ushort4 v;
    v.x = f2bf(acc[i][0]); v.y = f2bf(acc[i][1]);
    v.z = f2bf(acc[i][2]); v.w = f2bf(acc[i][3]);
    *(ushort4*)&McatT[(((size_t)b * L_ + l) * MSG2 + o) * N_ + w0 + tx * 4] = v;
  }
}

// ---------------- agg via 5 masked bf16 MFMA GEMMs, K-split 4 ----------------
__global__ __launch_bounds__(256) void k_agg_mfma(const float* __restrict__ g,
                                                  const int* __restrict__ e,
                                                  const unsigned short* __restrict__ McatT,
                                                  float* __restrict__ aggP) {
  __shared__ __align__(16) unsigned short Gt[64 * 40];
  __shared__ __align__(16) unsigned char  Et[64 * 40];
  __shared__ __align__(16) unsigned short Bl[L_][128 * 40];
  const int tid  = threadIdx.x;
  const int v0   = blockIdx.x * 64;
  const int ks   = blockIdx.y;
  const int b    = blockIdx.z;
  const int wid  = tid >> 6, lane = tid & 63;
  const int wr   = wid >> 1, wc = wid & 1;
  const int lr   = lane & 15, lg = lane >> 4;

  f32x4 acc[2][4];
  #pragma unroll
  for (int m = 0; m < 2; ++m)
    #pragma unroll
    for (int n = 0; n < 4; ++n) acc[m][n] = {0.f, 0.f, 0.f, 0.f};

  const int ar = tid >> 2, aq = (tid & 3) * 8;
  const int br = tid >> 1, bq = (tid & 1) * 16;
  const size_t grow = ((size_t)b * N_ + v0 + ar) * N_;

  for (int kk = 0; kk < 8; ++kk) {
    const int kbase = ks * 256 + kk * 32;
    {
      const float* gp = g + grow + kbase + aq;
      const int*   ep = e + grow + kbase + aq;
      float4 g0 = *(const float4*)gp, g1 = *(const float4*)(gp + 4);
      int4   e0 = *(const int4*)ep,  e1 = *(const int4*)(ep + 4);
      s16x8 gv;
      gv[0] = (short)f2bf(g0.x); gv[1] = (short)f2bf(g0.y);
      gv[2] = (short)f2bf(g0.z); gv[3] = (short)f2bf(g0.w);
      gv[4] = (short)f2bf(g1.x); gv[5] = (short)f2bf(g1.y);
      gv[6] = (short)f2bf(g1.z); gv[7] = (short)f2bf(g1.w);
      *(s16x8*)&Gt[ar * 40 + aq] = gv;
      unsigned int ew0 = (unsigned)(e0.x & 0xFF) | ((unsigned)(e0.y & 0xFF) << 8) |
                         ((unsigned)(e0.z & 0xFF) << 16) | ((unsigned)(e0.w & 0xFF) << 24);
      unsigned int ew1 = (unsigned)(e1.x & 0xFF) | ((unsigned)(e1.y & 0xFF) << 8) |
                         ((unsigned)(e1.z & 0xFF) << 16) | ((unsigned)(e1.w & 0xFF) << 24);
      uint2 ewv; ewv.x = ew0; ewv.y = ew1;
      *(uint2*)&Et[ar * 40 + aq] = ewv;
    }
    #pragma unroll
    for (int l = 0; l < L_; ++l) {
      const unsigned short* mp = McatT + (((size_t)b * L_ + l) * MSG2 + br) * N_ + kbase + bq;
      *(uint4*)&Bl[l][br * 40 + bq]     = *(const uint4*)mp;
      *(uint4*)&Bl[l][br * 40 + bq + 8] = *(const uint4*)(mp + 8);
    }
    __syncthreads();
    s16x8 gt[2]; uint2 et[2];
    #pragma unroll
    for (int m = 0; m < 2; ++m) {
      int row = wr * 32 + m * 16 + lr;
      gt[m] = *(const s16x8*)&Gt[row * 40 + lg * 8];
      et[m] = *(const uint2*)&Et[row * 40 + lg * 8];
    }
    #pragma unroll
    for (int l = 0; l < L_; ++l) {
      s16x8 bfr[4];
      #pragma unroll
      for (int n = 0; n < 4; ++n)
        bfr[n] = *(const s16x8*)&Bl[l][(wc * 64 + n * 16 + lr) * 40 + lg * 8];
      #pragma unroll
      for (int m = 0; m < 2; ++m) {
        unsigned int w0e = et[m].x, w1e = et[m].y;
        s16x8 af;
        af[0] = (((w0e      ) & 0xFFu) == (unsigned)l) ? gt[m][0] : (short)0;
        af[1] = (((w0e >>  8) & 0xFFu) == (unsigned)l) ? gt[m][1] : (short)0;
        af[2] = (((w0e >> 16) & 0xFFu) == (unsigned)l) ? gt[m][2] : (short)0;
        af[3] = (((w0e >> 24) & 0xFFu) == (unsigned)l) ? gt[m][3] : (short)0;
        af[4] = (((w1e      ) & 0xFFu) == (unsigned)l) ? gt[m][4] : (short)0;
        af[5] = (((w1e >>  8) & 0xFFu) == (unsigned)l) ? gt[m][5] : (short)0;
        af[6] = (((w1e >> 16) & 0xFFu) == (unsigned)l) ? gt[m][6] : (short)0;
        af[7] = (((w1e >> 24) & 0xFFu) == (unsigned)l) ? gt[m][7] : (short)0;
        #pragma unroll
        for (int n = 0; n < 4; ++n)
          acc[m][n] = __builtin_amdgcn_mfma_f32_16x16x32_bf16(af, bfr[n], acc[m][n], 0, 0, 0);
      }
    }
    __syncthreads();
  }
  float* op = aggP + ((size_t)ks * NODES + (size_t)b * N_ + v0) * MSG2;
  #pragma unroll
  for (int m = 0; m < 2; ++m)
    #pragma unroll
    for (int n = 0; n < 4; ++n)
      #pragma unroll
      for (int j = 0; j < 4; ++j) {
        int row = wr * 32 + m * 16 + lg * 4 + j;
        int col = wc * 64 + n * 16 + lr;
        op[(size_t)row * MSG2 + col] = acc[m][n][j];
      }
}

// ---------------- xprep: m[node][j] = sum of KSPLIT agg slabs (fp32) ----------------
__global__ __launch_bounds__(256) void k_xprep(const float* __restrict__ aggP,
                                               float* __restrict__ m) {
  const size_t slab = (size_t)NODES * MSG2;
  size_t i4 = ((size_t)blockIdx.x * 256 + threadIdx.x) * 4;
  float4 s0 = *(const float4*)&aggP[i4];
  float4 s1 = *(const float4*)&aggP[slab + i4];
  float4 s2 = *(const float4*)&aggP[2 * slab + i4];
  float4 s3 = *(const float4*)&aggP[3 * slab + i4];
  float4 s;
  s.x = s0.x + s1.x + s2.x + s3.x;
  s.y = s0.y + s1.y + s2.y + s3.y;
  s.z = s0.z + s1.z + s2.z + s3.z;
  s.w = s0.w + s1.w + s2.w + s3.w;
  *(float4*)&m[i4] = s;
}

// ---------------- gates GEMM (fp32 SIMT): gates[row][z*384+c] = X_z @ W_z ----------------
__global__ __launch_bounds__(256) void k_gates_f32(const float* __restrict__ m,
                                                   const float* __restrict__ h,
                                                   const float* __restrict__ Wi,
                                                   const float* __restrict__ Wh,
                                                   float* __restrict__ gates) {
  __shared__ float At[32][64];   // [k][row]
  __shared__ float Bt[32][64];   // [k][col]
  const int z = blockIdx.z;
  const float* X = z ? h : m;
  const float* W = z ? Wh : Wi;
  const int tx = threadIdx.x & 15;
  const int ty = threadIdx.x >> 4;
  const int r0 = blockIdx.y * 64;
  const int c0 = blockIdx.x * 64;
  float acc[4][4] = {};
  const int q    = threadIdx.x * 8;
  const int srow = q >> 5;          // 0..63
  const int sk0  = q & 31;          // 0,8,16,24
  const int bk   = threadIdx.x >> 3;        // 0..31
  const int bc   = (threadIdx.x & 7) * 8;   // 0..56
  for (int kc = 0; kc < 128; kc += 32) {
    const float* xs = X + (size_t)(r0 + srow) * 128 + kc + sk0;
    float4 a0 = *(const float4*)xs;
    float4 a1 = *(const float4*)(xs + 4);
    At[sk0+0][srow] = a0.x; At[sk0+1][srow] = a0.y;
    At[sk0+2][srow] = a0.z; At[sk0+3][srow] = a0.w;
    At[sk0+4][srow] = a1.x; At[sk0+5][srow] = a1.y;
    At[sk0+6][srow] = a1.z; At[sk0+7][srow] = a1.w;
    const float* wsrc = W + (size_t)(kc + bk) * 384 + c0 + bc;
    *(float4*)&Bt[bk][bc]     = *(const float4*)wsrc;
    *(float4*)&Bt[bk][bc + 4] = *(const float4*)(wsrc + 4);
    __syncthreads();
    #pragma unroll
    for (int k = 0; k < 32; ++k) {
      float4 av = *(const float4*)&At[k][ty * 4];
      float4 bv = *(const float4*)&Bt[k][tx * 4];
      acc[0][0] += av.x*bv.x; acc[0][1] += av.x*bv.y; acc[0][2] += av.x*bv.z; acc[0][3] += av.x*bv.w;
      acc[1][0] += av.y*bv.x; acc[1][1] += av.y*bv.y; acc[1][2] += av.y*bv.z; acc[1][3] += av.y*bv.w;
      acc[2][0] += av.z*bv.x; acc[2][1] += av.z*bv.y; acc[2][2] += av.z*bv.z; acc[2][3] += av.z*bv.w;
      acc[3][0] += av.w*bv.x; acc[3][1] += av.w*bv.y; acc[3][2] += av.w*bv.z; acc[3][3] += av.w*bv.w;
    }
    __syncthreads();
  }
  #pragma unroll
  for (int i = 0; i < 4; ++i) {
    float4 v = make_float4(acc[i][0], acc[i][1], acc[i][2], acc[i][3]);
    *(float4*)&gates[(size_t)(r0 + ty*4 + i) * 768 + z * 384 + c0 + tx*4] = v;
  }
}

// ---------------- GRU elementwise ----------------
__global__ __launch_bounds__(256) void k_gru_elt(const float* __restrict__ gates,
                                                 const float* __restrict__ bi,
                                                 const float* __restrict__ bh,
                                                 const float* __restrict__ maskA,
                                                 float* __restrict__ h) {
  const int t = threadIdx.x;
  const int node = blockIdx.x * 8 + (t >> 5);
  const int j4 = (t & 31) * 4;
  const size_t gb = (size_t)node * 768;
  float4 gir = *(const float4*)&gates[gb + j4];
  float4 giz = *(const float4*)&gates[gb + 128 + j4];
  float4 gin = *(const float4*)&gates[gb + 256 + j4];
  float4 ghr = *(const float4*)&gates[gb + 384 + j4];
  float4 ghz = *(const float4*)&gates[gb + 512 + j4];
  float4 ghn = *(const float4*)&gates[gb + 640 + j4];
  float4 bir = *(const float4*)&bi[j4];
  float4 biz = *(const float4*)&bi[128 + j4];
  float4 bin = *(const float4*)&bi[256 + j4];
  float4 bhr = *(const float4*)&bh[j4];
  float4 bhz = *(const float4*)&bh[128 + j4];
  float4 bhn = *(const float4*)&bh[256 + j4];
  float4 hv = *(const float4*)&h[(size_t)node * 128 + j4];
  float m = maskA[node];
  float4 ho;
  {
    float r = sigmoidf_(gir.x + bir.x + ghr.x + bhr.x);
    float z = sigmoidf_(giz.x + biz.x + ghz.x + bhz.x);
    float nn = tanhf(gin.x + bin.x + r * (ghn.x + bhn.x));
    ho.x = ((1.f - z) * nn + z * hv.x) * m;
  }
  {
    float r = sigmoidf_(gir.y + bir.y + ghr.y + bhr.y);
    float z = sigmoidf_(giz.y + biz.y + ghz.y + bhz.y);
    float nn = tanhf(gin.y + bin.y + r * (ghn.y + bhn.y));
    ho.y = ((1.f - z) * nn + z * hv.y) * m;
  }
  {
    float r = sigmoidf_(gir.z + bir.z + ghr.z + bhr.z);
    float z = sigmoidf_(giz.z + biz.z + ghz.z + bhz.z);
    float nn = tanhf(gin.z + bin.z + r * (ghn.z + bhn.z));
    ho.z = ((1.f - z) * nn + z * hv.z) * m;
  }
  {
    float r = sigmoidf_(gir.w + bir.w + ghr.w + bhr.w);
    float z = sigmoidf_(giz.w + biz.w + ghz.w + bhz.w);
    float nn = tanhf(gin.w + bin.w + r * (ghn.w + bhn.w));
    ho.w = ((1.f - z) * nn + z * hv.w) * m;
  }
  *(float4*)&h[(size_t)node * 128 + j4] = ho;
}

// ---------------- readout stage 1: PT[c][node] = ([hT,h0] @ Wcat)[node][c] ----------------
// Wcat[256][24]: col t<12 -> Wg[:,t] over [hT,h0]; col 12+t -> Wo[:,t] over hT (0 for k>=128).
__global__ __launch_bounds__(256) void k_readP(const float* __restrict__ h,
                                               const float* __restrict__ h0,
                                               const float* __restrict__ Wg,
                                               const float* __restrict__ Wo,
                                               float* __restrict__ PT) {
  __shared__ float Xt[64][65];   // [node][k-chunk]
  __shared__ float Wt[64][25];   // [k][c], pad
  const int tid = threadIdx.x;
  const int node0 = blockIdx.x * 64;
  const int row = tid >> 2;          // 0..63 node
  const int cg  = tid & 3;           // col group: cols cg*6 .. cg*6+5
  float acc[6] = {0.f, 0.f, 0.f, 0.f, 0.f, 0.f};
  const int sr = tid >> 2;           // staging node
  const int sk = (tid & 3) * 16;     // staging k offset (16 floats)
  #pragma unroll
  for (int kb = 0; kb < 4; ++kb) {
    // stage X: k-chunk kb*64..+64 ; kb 0,1 -> h ; kb 2,3 -> h0
    const float* src = (kb < 2 ? h : h0) + (size_t)(node0 + sr) * 128 + (kb & 1) * 64 + sk;
    #pragma unroll
    for (int q = 0; q < 4; ++q)
      *(float4*)&Xt[sr][sk + q * 4] = *(const float4*)(src + q * 4);
    // stage Wcat rows kb*64..+64
    #pragma unroll
    for (int j = 0; j < 6; ++j) {
      int idx = tid * 6 + j;           // 0..1535
      int rk = idx / 24;               // 0..63
      int c24 = idx - rk * 24;
      int gk = kb * 64 + rk;
      float wv;
      if (c24 < 12) wv = Wg[(size_t)gk * TGT_ + c24];
      else          wv = (gk < 128) ? Wo[(size_t)gk * TGT_ + (c24 - 12)] : 0.f;
      Wt[rk][c24] = wv;
    }
    __syncthreads();
    #pragma unroll 8
    for (int k = 0; k < 64; ++k) {
      float x = Xt[row][k];
      #pragma unroll
      for (int j = 0; j < 6; ++j)
        acc[j] += x * Wt[k][cg * 6 + j];
    }
    __syncthreads();
  }
  #pragma unroll
  for (int j = 0; j < 6; ++j)
    PT[(size_t)(cg * 6 + j) * NODES + node0 + row] = acc[j];
}

// ---------------- readout stage 2: out[b][t] = sum_n sigmoid(p1+bg)*(p2+bo)*maskR ----------------
__global__ __launch_bounds__(256) void k_readR(const float* __restrict__ PT,
                                               const float* __restrict__ maskR,
                                               const float* __restrict__ bg,
                                               const float* __restrict__ bo,
                                               float* __restrict__ out) {
  __shared__ float red[256];
  const int tid = threadIdx.x;
  const int b = blockIdx.x / TGT_;
  const int t = blockIdx.x - b * TGT_;
  const float bgt = bg[t], bot = bo[t];
  float s = 0.f;
  #pragma unroll
  for (int i = 0; i < 4; ++i) {
    int node = b * N_ + i * 256 + tid;
    float p1 = PT[(size_t)t * NODES + node] + bgt;
    float p2 = PT[(size_t)(12 + t) * NODES + node] + bot;
    s += sigmoidf_(p1) * p2 * maskR[node];
  }
  red[tid] = s;
  __syncthreads();
  #pragma unroll
  for (int off = 128; off > 0; off >>= 1) {
    if (tid < off) red[tid] += red[tid + off];
    __syncthreads();
  }
  if (tid == 0) out[b * TGT_ + t] = red[0];
}

extern "C" void kernel_launch(void* const* d_in, const int* in_sizes, int n_in,
                              void* d_out, int out_size, void* d_ws, size_t ws_size,
                              hipStream_t stream) {
  (void)in_sizes; (void)n_in; (void)out_size; (void)ws_size;
  const float* g    = (const float*)d_in[0];
  const float* h_in = (const float*)d_in[1];
  const int*   e    = (const int*)d_in[2];
  const float* A    = (const float*)d_in[3];
  const float* Wi   = (const float*)d_in[4];
  const float* Wh   = (const float*)d_in[5];
  const float* bi   = (const float*)d_in[6];
  const float* bh   = (const float*)d_in[7];
  const float* Wg   = (const float*)d_in[8];
  const float* bg   = (const float*)d_in[9];
  const float* Wo   = (const float*)d_in[10];
  const float* bo   = (const float*)d_in[11];
  float* out = (float*)d_out;
  float* ws  = (float*)d_ws;

  // workspace layout (fp32 elements unless noted):
  float* h     = ws;                                   // 1,048,576
  float* h0    = h + (size_t)NODES * H_;               // 1,048,576
  float* maskA = h0 + (size_t)NODES * H_;              // 8192
  float* maskR = maskA + NODES;                        // 8192
  float* Acat  = maskR + NODES;                        // 81,920
  float* m     = Acat + 128 * CAT_;                    // 1,048,576
  float* aggP  = m + (size_t)NODES * MSG2;             // KSPLIT * 1,048,576 (16.8 MB)
  unsigned short* McatT = (unsigned short*)(aggP + (size_t)KSPLIT * NODES * MSG2); // 10.5 MB
  // gates (25.2 MB) overlays aggP+McatT (27.3 MB): aggP dead after k_xprep,
  // McatT dead after k_agg_mfma.
  float* gates = aggP;
  // PT (24*8192 f = 786 KB) reuses m (dead after last k_gates_f32).
  float* PT = m;

  k_init<<<NODES / 4, 256, 0, stream>>>(h_in, h, h0, maskA, maskR);
  k_acat<<<(128 * CAT_ + 255) / 256, 256, 0, stream>>>(A, Acat);
  for (int layer = 0; layer < NLAYERS_; ++layer) {
    k_gemmT<<<dim3(CAT_ / 64, NODES / 64), 256, 0, stream>>>(h, Acat, McatT);
    k_agg_mfma<<<dim3(N_ / 64, KSPLIT, B_), 256, 0, stream>>>(g, e, McatT, aggP);
    k_xprep<<<(NODES * MSG2 / 4) / 256, 256, 0, stream>>>(aggP, m);
    k_gates_f32<<<dim3(384 / 64, NODES / 64, 2), 256, 0, stream>>>(m, h, Wi, Wh, gates);
    k_gru_elt<<<NODES / 8, 256, 0, stream>>>(gates, bi, bh, maskA, h);
  }
  k_readP<<<NODES / 64, 256, 0, stream>>>(h, h0, Wg, Wo, PT);
  k_readR<<<B_ * TGT_, 256, 0, stream>>>(PT, maskR, bg, bo, out);
}